// Round 7
// baseline (358.557 us; speedup 1.0000x reference)
//
#include <hip/hip_runtime.h>

// Problem constants (from reference)
#define NN   100000
#define EE   1600000
#define GG   500
#define NPGc 200
#define HH   64
#define NPERMc 3
#define C1   16384    // binning chunk (edges per block)
#define HST  74       // H tile stride (f32)
#define BSTRIDE 4096  // fixed token-bucket stride per graph
#define EB   98       // binning blocks
#define XWB  782      // xw blocks (128 rows each)

typedef __fp16   h16x2 __attribute__((ext_vector_type(2)));   // pkrtz result type
typedef _Float16 f16x4 __attribute__((ext_vector_type(4)));
typedef _Float16 f16x8 __attribute__((ext_vector_type(8)));
typedef float    f32x4 __attribute__((ext_vector_type(4)));

// ---------------------------------------------------------------------------
// f32 -> f16 hi/lo conversion (validated r4-r6)
// ---------------------------------------------------------------------------
__device__ __forceinline__ void cvt_hilo(f32x4 a, f32x4 b, f16x8& hi, f16x8& lo) {
    float f[8] = {a[0], a[1], a[2], a[3], b[0], b[1], b[2], b[3]};
#pragma unroll
    for (int j = 0; j < 8; j += 2) {
        h16x2 h = __builtin_amdgcn_cvt_pkrtz(f[j], f[j + 1]);
        h16x2 l = __builtin_amdgcn_cvt_pkrtz(f[j] - (float)h[0], f[j + 1] - (float)h[1]);
        hi[j] = (_Float16)h[0]; hi[j + 1] = (_Float16)h[1];
        lo[j] = (_Float16)l[0]; lo[j + 1] = (_Float16)l[1];
    }
}

__device__ __forceinline__ void cvt_hilo4(const float (&v)[4], f16x4& hv, f16x4& lv) {
#pragma unroll
    for (int i = 0; i < 4; i += 2) {
        h16x2 h = __builtin_amdgcn_cvt_pkrtz(v[i], v[i + 1]);
        h16x2 l = __builtin_amdgcn_cvt_pkrtz(v[i] - (float)h[0], v[i + 1] - (float)h[1]);
        hv[i] = (_Float16)h[0]; hv[i + 1] = (_Float16)h[1];
        lv[i] = (_Float16)l[0]; lv[i + 1] = (_Float16)l[1];
    }
}

// build one W hi/lo B-frag slot (validated r4-r6 layout) from f32 weights
__device__ __forceinline__ f16x8 wfrag_slot(const float* __restrict__ src, int kstep, int ct,
                                            int term, int mq, int qq) {
    f16x8 v;
#pragma unroll
    for (int j = 0; j < 8; ++j) {
        float wv = src[(kstep * 32 + qq * 8 + j) * 64 + ct * 16 + mq];
        _Float16 hi = (_Float16)wv;
        v[j] = term ? (_Float16)(wv - (float)hi) : hi;
    }
    return v;
}

// ---------------------------------------------------------------------------
// k_pre: blocks [0,EB) bin edges into fixed-stride per-graph u16 token buckets
// (token = lsrc | ldst<<8). blocks [EB, EB+XWB): xW = x @ W1[0:128] via hi/lo
// f16 MFMA, W1 B-frags built inline in LDS (no separate wprep kernel).
// ---------------------------------------------------------------------------
__global__ __launch_bounds__(512) void k_pre(const int* __restrict__ ei, int* __restrict__ gcnt,
                                             unsigned short* __restrict__ gtok,
                                             const float* __restrict__ w1,
                                             const float* __restrict__ x, float* __restrict__ xW) {
    __shared__ __align__(16) char shmem[40960];
    int t = threadIdx.x;

    if (blockIdx.x >= EB) {   // ---- xw part ----
        _Float16* wfl = (_Float16*)shmem;    // 32 chunks x 512 f16 = 32 KB
        for (int i = t; i < 2048; i += 512) {
            int c = i >> 6, lane2 = i & 63;
            ((f16x8*)wfl)[i] = wfrag_slot(w1, c & 3, (c >> 2) & 3, c >> 4, lane2 & 15, lane2 >> 4);
        }
        __syncthreads();
        int lane = t & 63, w = t >> 6;
        int rbase = (blockIdx.x - EB) * 128 + w * 16;
        int m = lane & 15, q = lane >> 4;
        int rowc = min(rbase + m, NN - 1);
        f16x8 Ah[4], Al[4];
#pragma unroll
        for (int ks = 0; ks < 4; ++ks) {
            const float* ar = x + (size_t)rowc * 128 + ks * 32 + q * 8;
            f32x4 f0 = *(const f32x4*)ar;
            f32x4 f1 = *(const f32x4*)(ar + 4);
            cvt_hilo(f0, f1, Ah[ks], Al[ks]);
        }
#pragma unroll
        for (int ct = 0; ct < 4; ++ct) {
            f32x4 acc = {0.f, 0.f, 0.f, 0.f};
#pragma unroll
            for (int ks = 0; ks < 4; ++ks) {
                f16x8 Bh = ((const f16x8*)wfl)[((0 * 4 + ct) * 4 + ks) * 64 + lane];
                f16x8 Bl = ((const f16x8*)wfl)[((1 * 4 + ct) * 4 + ks) * 64 + lane];
                acc = __builtin_amdgcn_mfma_f32_16x16x32_f16(Ah[ks], Bh, acc, 0, 0, 0);
                acc = __builtin_amdgcn_mfma_f32_16x16x32_f16(Al[ks], Bh, acc, 0, 0, 0);
                acc = __builtin_amdgcn_mfma_f32_16x16x32_f16(Ah[ks], Bl, acc, 0, 0, 0);
            }
#pragma unroll
            for (int i = 0; i < 4; ++i) {
                int r = rbase + q * 4 + i;
                if (r < NN) xW[(size_t)r * 64 + ct * 16 + m] = acc[i];
            }
        }
        return;
    }

    // ---- binning part (validated r5/r6) ----
    unsigned short* stag = (unsigned short*)shmem;          // 32768 B
    int* h   = (int*)(shmem + 32768);                       // 512 ints
    int* esc = h + 512;
    int* cur = esc + 512;
    int* gb  = cur + 512;
    int base = blockIdx.x * C1;
    int nE = min(C1, EE - base);
    h[t] = 0; cur[t] = 0;
    __syncthreads();
    for (int i = t; i < nE; i += 512) atomicAdd(&h[ei[base + i] / NPGc], 1);
    __syncthreads();
    esc[t] = h[t];
    __syncthreads();
    for (int off = 1; off < 512; off <<= 1) {
        int u = (t >= off) ? esc[t - off] : 0;
        __syncthreads();
        esc[t] += u;
        __syncthreads();
    }
    esc[t] -= h[t];
    if (t < GG && h[t] > 0) gb[t] = atomicAdd(&gcnt[t], h[t]);
    __syncthreads();
    for (int i = t; i < nE; i += 512) {
        int s = ei[base + i], d = ei[EE + base + i];
        int g = s / NPGc;
        int ls = s - g * NPGc, ld = d - g * NPGc;
        int pos = esc[g] + atomicAdd(&cur[g], 1);
        stag[pos] = (unsigned short)(ls | (ld << 8));
    }
    __syncthreads();
    int w = t >> 6, lane = t & 63;
    for (int g = w; g < GG; g += 8) {
        int c = h[g]; if (!c) continue;
        int lb = esc[g], off = gb[g];
        int lim = min(c, BSTRIDE - off);
        for (int j = lane; j < lim; j += 64) gtok[(size_t)g * BSTRIDE + off + j] = stag[lb + j];
    }
}

// ---------------------------------------------------------------------------
// adjacency bytes (8) -> exact f16x8 A-fragment
// ---------------------------------------------------------------------------
__device__ __forceinline__ f16x8 cvt_a8(uint2 v) {
    f16x8 r;
#pragma unroll
    for (int k = 0; k < 4; ++k) r[k] = (_Float16)(float)((v.x >> (8 * k)) & 255u);
#pragma unroll
    for (int k = 0; k < 4; ++k) r[4 + k] = (_Float16)(float)((v.y >> (8 * k)) & 255u);
    return r;
}

// ---------------------------------------------------------------------------
// dense conv via MFMA, 4m x 2n wave tiling: each wave owns m-tiles
// [mtbase, mtbase+nmt) and column-pair wn -> reads only its B half, 8 MFMAs
// per B hi/lo load pair.
// ---------------------------------------------------------------------------
template <bool POOL>
__device__ __forceinline__ void conv_mfma(const _Float16* __restrict__ Tfh,
                                          const _Float16* __restrict__ Tfl,
                                          float* __restrict__ H,
                                          const f16x8 (&Af)[4][7], int lane, int m, int q,
                                          int wn, int mtbase, int nmt,
                                          const float (&dvv)[4][4], const float (&bias)[4],
                                          float (&poolv)[4]) {
    f32x4 acc[4][2];
#pragma unroll
    for (int mi = 0; mi < 4; ++mi)
#pragma unroll
        for (int c = 0; c < 2; ++c) acc[mi][c] = (f32x4){0.f, 0.f, 0.f, 0.f};

#pragma unroll
    for (int ks = 0; ks < 7; ++ks) {
#pragma unroll
        for (int c = 0; c < 2; ++c) {
            int ct = wn * 2 + c;
            f16x8 Bh = ((const f16x8*)Tfh)[(ks * 4 + ct) * 64 + lane];
            f16x8 Bl = ((const f16x8*)Tfl)[(ks * 4 + ct) * 64 + lane];
#pragma unroll
            for (int mi = 0; mi < 4; ++mi) {
                if (mi >= nmt) break;
                acc[mi][c] = __builtin_amdgcn_mfma_f32_16x16x32_f16(Af[mi][ks], Bh, acc[mi][c], 0, 0, 0);
                acc[mi][c] = __builtin_amdgcn_mfma_f32_16x16x32_f16(Af[mi][ks], Bl, acc[mi][c], 0, 0, 0);
            }
        }
    }
#pragma unroll
    for (int mi = 0; mi < 4; ++mi) {
        if (mi >= nmt) break;
        int rbase = (mtbase + mi) * 16 + q * 4;
#pragma unroll
        for (int c = 0; c < 2; ++c) {
            int ct = wn * 2 + c;
            if (!POOL) {
#pragma unroll
                for (int i = 0; i < 4; ++i)
                    H[(rbase + i) * HST + ct * 16 + m] =
                        fmaxf(fmaf(dvv[mi][i], acc[mi][c][i], bias[ct]), 0.f);
            } else {
                float pl = 0.f;
#pragma unroll
                for (int i = 0; i < 4; ++i) {
                    float o = fmaxf(fmaf(dvv[mi][i], acc[mi][c][i], bias[ct]), 0.f);
                    if (rbase + i < NPGc) pl += o;
                }
                poolv[ct] += pl;
            }
        }
    }
}

// ---------------------------------------------------------------------------
// dense GEMM: T(frags) = dv * (H @ W), same 4m x 2n tiling; output written
// directly as hi/lo B-frags (validated r6 lane mapping, generic in mt).
// ---------------------------------------------------------------------------
__device__ __forceinline__ void gemm_mfma(const float* __restrict__ H,
                                          _Float16* __restrict__ Tfh, _Float16* __restrict__ Tfl,
                                          const _Float16* __restrict__ wf, int lane,
                                          int m, int q, int wn, int mtbase, int nmt,
                                          const float (&dvv)[4][4]) {
#pragma unroll
    for (int mi = 0; mi < 4; ++mi) {
        if (mi >= nmt) break;
        int mt = mtbase + mi;
        f16x8 Ah[2], Al[2];
#pragma unroll
        for (int ks = 0; ks < 2; ++ks) {
            const float* ap = H + (mt * 16 + m) * HST + ks * 32 + 8 * q;
            float2 u0 = *(const float2*)ap;
            float2 u1 = *(const float2*)(ap + 2);
            float2 u2 = *(const float2*)(ap + 4);
            float2 u3 = *(const float2*)(ap + 6);
            f32x4 a = {u0.x, u0.y, u1.x, u1.y};
            f32x4 b = {u2.x, u2.y, u3.x, u3.y};
            cvt_hilo(a, b, Ah[ks], Al[ks]);
        }
        int quad = (2 * mt + (q >> 1)) & 3;
        int j0 = (q & 1) << 2;
        int lanep = m + (quad << 4);
#pragma unroll
        for (int c = 0; c < 2; ++c) {
            int ct = wn * 2 + c;
            f32x4 acc = {0.f, 0.f, 0.f, 0.f};
#pragma unroll
            for (int ks = 0; ks < 2; ++ks) {
                f16x8 Bh = ((const f16x8*)wf)[((0 * 4 + ct) * 2 + ks) * 64 + lane];
                f16x8 Bl = ((const f16x8*)wf)[((1 * 4 + ct) * 2 + ks) * 64 + lane];
                acc = __builtin_amdgcn_mfma_f32_16x16x32_f16(Ah[ks], Bh, acc, 0, 0, 0);
                acc = __builtin_amdgcn_mfma_f32_16x16x32_f16(Al[ks], Bh, acc, 0, 0, 0);
                acc = __builtin_amdgcn_mfma_f32_16x16x32_f16(Ah[ks], Bl, acc, 0, 0, 0);
            }
            float o[4];
#pragma unroll
            for (int i = 0; i < 4; ++i) o[i] = acc[i] * dvv[mi][i];
            f16x4 hv, lv;
            cvt_hilo4(o, hv, lv);
            int off = ((mt >> 1) * 4 + ct) * 512 + lanep * 8 + j0;
            *(f16x4*)(Tfh + off) = hv;
            *(f16x4*)(Tfl + off) = lv;
        }
    }
}

// ---------------------------------------------------------------------------
// Fused kernel: one block (512 thr, 8 waves) per graph; W2/W3 frags built
// inline; head MLP folded in. ~158 KB LDS -> 1 block/CU, VGPR-heavy OK at
// 2 waves/SIMD.
// ---------------------------------------------------------------------------
__global__ __launch_bounds__(512, 2) void k_fused(
    const float* __restrict__ xW, const float* __restrict__ perm,
    const float* __restrict__ w1,
    const float* __restrict__ b1, const float* __restrict__ b2, const float* __restrict__ b3,
    const float* __restrict__ w2, const float* __restrict__ w3,
    const int* __restrict__ gcnt, const unsigned short* __restrict__ gtok,
    const float* __restrict__ a1w, const float* __restrict__ a1b,
    const float* __restrict__ a2w, const float* __restrict__ a2b,
    float* __restrict__ out) {
    __shared__ __align__(16) float Hm[15392];            // union: A8 build (46592B) / H f32
    __shared__ __align__(16) _Float16 Tfh[28 * 512];     // T hi frags  (28 KB)
    __shared__ __align__(16) _Float16 Tfl[28 * 512];     // T lo frags  (28 KB)
    __shared__ __align__(16) _Float16 wlds[32 * 512];    // W2 chunks 0-15, W3 16-31 (32 KB)
    __shared__ float w1r[640];
    __shared__ float dv[224];
    __shared__ float pool[8 * 64];
    __shared__ unsigned char idsl[672];

    unsigned char* A8  = (unsigned char*)Hm;
    unsigned int*  A32 = (unsigned int*)Hm;

    int g = blockIdx.x, t = threadIdx.x;
    int lane = t & 63, w = t >> 6;
    int m = lane & 15, q = lane >> 4;
    int wm = w >> 1, wn = w & 1;
    int mtbase = (wm == 0) ? 0 : 3 * wm + 1;   // {0,4,7,10}
    int nmt = (wm == 0) ? 4 : 3;
    int nbase = g * NPGc;
    int cnt = min(gcnt[g], BSTRIDE);
    const unsigned short* tok = gtok + (size_t)g * BSTRIDE;

    // build W2/W3 frags inline (w2/w3 are L2-hot across 500 blocks)
    for (int i = t; i < 2048; i += 512) {
        int c = i >> 6, lane2 = i & 63;
        const float* src = (c >= 16) ? w3 : w2;
        int c4 = c & 15;
        ((f16x8*)wlds)[i] = wfrag_slot(src, c4 & 1, (c4 >> 1) & 3, c4 >> 3, lane2 & 15, lane2 >> 4);
    }
    for (int i = t; i < 640; i += 512) w1r[i] = w1[128 * 64 + i];
    for (int i = t; i < 2912; i += 512) ((uint4*)A8)[i] = make_uint4(0, 0, 0, 0);
    __syncthreads();
    // build adjacency (u8 packed atomics) + self-loops
    for (int i = t; i < cnt; i += 512) {
        int tk = tok[i];
        int addr = (tk >> 8) * 224 + (tk & 255);
        atomicAdd(&A32[addr >> 2], 1u << ((addr & 3) * 8));
    }
    if (t < NPGc) { int a = t * 225; atomicAdd(&A32[a >> 2], 1u << ((a & 3) * 8)); }
    // one-hot ids for the 3 perms
    for (int i = t; i < 672; i += 512) {
        int p = i / 224, nd = i - p * 224;
        int id = 0;
        if (nd < NPGc) {
            const float* pp = perm + ((size_t)p * NN + nbase + nd) * 10;
            float best = pp[0];
#pragma unroll
            for (int k = 1; k < 10; ++k) { float v = pp[k]; if (v > best) { best = v; id = k; } }
        }
        idsl[i] = (unsigned char)id;
    }
    __syncthreads();
    // deg (row sums incl. self) -> dv
    if (t < 224) {
        unsigned s = 0;
        if (t < 208)
            for (int i = 0; i < 56; ++i) {
                unsigned v = A32[t * 56 + i];
                s += (v & 255u) + ((v >> 8) & 255u) + ((v >> 16) & 255u) + (v >> 24);
            }
        dv[t] = s ? rsqrtf((float)s) : 0.f;
    }
    // load adjacency A-fragments into VGPRs (persist whole kernel)
    f16x8 Af[4][7];
#pragma unroll
    for (int mi = 0; mi < 4; ++mi) {
        if (mi >= nmt) break;
#pragma unroll
        for (int ks = 0; ks < 7; ++ks) {
            uint2 v = *(const uint2*)(A8 + ((mtbase + mi) * 16 + m) * 224 + ks * 32 + q * 8);
            Af[mi][ks] = cvt_a8(v);
        }
    }
    __syncthreads();   // A8 region now dead -> H takes over

    float dvv[4][4];
#pragma unroll
    for (int mi = 0; mi < 4; ++mi)
#pragma unroll
        for (int i = 0; i < 4; ++i)
            dvv[mi][i] = (mi < nmt) ? dv[(mtbase + mi) * 16 + q * 4 + i] : 0.f;
    float bb1[4], bb2[4], bb3[4];
#pragma unroll
    for (int ct = 0; ct < 4; ++ct) {
        bb1[ct] = b1[ct * 16 + m]; bb2[ct] = b2[ct * 16 + m]; bb3[ct] = b3[ct * 16 + m];
    }

    float poolv[4] = {0.f, 0.f, 0.f, 0.f};

    for (int p = 0; p < NPERMc; ++p) {
        // conv1 input -> T frags: val = dv*(xW + w1row[id]); wave w owns nodes [28w, 28w+28)
        {
            const unsigned char* ids = idsl + p * 224;
            for (int nd0 = w * 28; nd0 < w * 28 + 28; nd0 += 4) {
                float vals[4];
#pragma unroll
                for (int i = 0; i < 4; ++i) {
                    int nd = nd0 + i;
                    float v = 0.f;
                    if (nd < NPGc) {
                        int id = ids[nd];
                        v = dv[nd] * (xW[(size_t)(nbase + nd) * 64 + lane] + w1r[id * 64 + lane]);
                    }
                    vals[i] = v;
                }
                f16x4 hv, lv;
                cvt_hilo4(vals, hv, lv);
                int c = (nd0 >> 5) * 4 + (lane >> 4);
                int lanep = (lane & 15) + (((nd0 & 31) >> 3) << 4);
                int off = c * 512 + lanep * 8 + (nd0 & 7);
                *(f16x4*)(Tfh + off) = hv;
                *(f16x4*)(Tfl + off) = lv;
            }
        }
        __syncthreads();
        conv_mfma<false>(Tfh, Tfl, Hm, Af, lane, m, q, wn, mtbase, nmt, dvv, bb1, poolv);
        __syncthreads();
        gemm_mfma(Hm, Tfh, Tfl, wlds, lane, m, q, wn, mtbase, nmt, dvv);            // W2
        __syncthreads();
        conv_mfma<false>(Tfh, Tfl, Hm, Af, lane, m, q, wn, mtbase, nmt, dvv, bb2, poolv);
        __syncthreads();
        gemm_mfma(Hm, Tfh, Tfl, wlds + 16 * 512, lane, m, q, wn, mtbase, nmt, dvv); // W3
        __syncthreads();
        conv_mfma<true>(Tfh, Tfl, Hm, Af, lane, m, q, wn, mtbase, nmt, dvv, bb3, poolv);
        __syncthreads();
    }

    // reduce pool: over q-groups (shfl) then over waves (LDS), then head MLP
#pragma unroll
    for (int ct = 0; ct < 4; ++ct) {
        float v = poolv[ct];
        v += __shfl_xor(v, 16);
        v += __shfl_xor(v, 32);
        if (q == 0) pool[w * 64 + ct * 16 + m] = v;
    }
    __syncthreads();
    if (t < 64) {
        float tot = 0.f;
#pragma unroll
        for (int i = 0; i < 8; ++i) tot += pool[i * 64 + t];
        pool[t] = tot * (1.0f / (NPGc * NPERMc));   // gsum
    }
    __syncthreads();
    if (t < 16) {
        float a = a1b[t];
        for (int k = 0; k < 64; ++k) a = fmaf(pool[k], a1w[k * 16 + t], a);
        pool[64 + t] = fmaxf(a, 0.f);
    }
    __syncthreads();
    if (t == 0) {
        float o = a2b[0];
#pragma unroll
        for (int i = 0; i < 16; ++i) o = fmaf(pool[64 + i], a2w[i], o);
        out[g] = o;
    }
}

// ---------------------------------------------------------------------------

static inline size_t alignup(size_t x) { return (x + 255) & ~(size_t)255; }

extern "C" void kernel_launch(void* const* d_in, const int* in_sizes, int n_in,
                              void* d_out, int out_size, void* d_ws, size_t ws_size,
                              hipStream_t stream) {
    const float* x    = (const float*)d_in[0];
    const int*   ei   = (const int*)d_in[1];
    // d_in[2] = batch_ids (unused: graphs are exactly 200 nodes each)
    const float* perm = (const float*)d_in[3];
    const float* w1   = (const float*)d_in[4];
    const float* b1   = (const float*)d_in[5];
    const float* w2   = (const float*)d_in[6];
    const float* b2   = (const float*)d_in[7];
    const float* w3   = (const float*)d_in[8];
    const float* b3   = (const float*)d_in[9];
    const float* a1w  = (const float*)d_in[10];
    const float* a1b  = (const float*)d_in[11];
    const float* a2w  = (const float*)d_in[12];
    const float* a2b  = (const float*)d_in[13];
    float* out = (float*)d_out;

    char* p = (char*)d_ws;
    auto take = [&](size_t bytes) { char* r = p; p += alignup(bytes); return r; };
    float*          xW   = (float*)take((size_t)NN * 64 * 4);
    unsigned short* gtok = (unsigned short*)take((size_t)GG * BSTRIDE * 2);
    int*            gcnt = (int*)take(512 * 4);
    (void)hipMemsetAsync(gcnt, 0, 512 * 4, stream);

    k_pre<<<EB + XWB, 512, 0, stream>>>(ei, gcnt, gtok, w1, x, xW);
    k_fused<<<GG, 512, 0, stream>>>(xW, perm, w1, b1, b2, b3, w2, w3,
                                    gcnt, gtok, a1w, a1b, a2w, a2b, out);
}

// Round 8
// 319.101 us; speedup vs baseline: 1.1236x; 1.1236x over previous
//
#include <hip/hip_runtime.h>

// Problem constants (from reference)
#define NN   100000
#define EE   1600000
#define GG   500
#define NPGc 200
#define NPERMc 3
#define ASTRIDE (208 * 224)   // adjacency slab bytes per graph (rows=dst 0..207, cols=src 0..223)

typedef __fp16   h16x2 __attribute__((ext_vector_type(2)));   // pkrtz result type
typedef _Float16 f16x4 __attribute__((ext_vector_type(4)));
typedef _Float16 f16x8 __attribute__((ext_vector_type(8)));
typedef float    f32x4 __attribute__((ext_vector_type(4)));

// ---------------------------------------------------------------------------
// f32 -> f16 hi/lo conversion (validated r4-r7; used only in k_xw 3-term path)
// ---------------------------------------------------------------------------
__device__ __forceinline__ void cvt_hilo(f32x4 a, f32x4 b, f16x8& hi, f16x8& lo) {
    float f[8] = {a[0], a[1], a[2], a[3], b[0], b[1], b[2], b[3]};
#pragma unroll
    for (int j = 0; j < 8; j += 2) {
        h16x2 h = __builtin_amdgcn_cvt_pkrtz(f[j], f[j + 1]);
        h16x2 l = __builtin_amdgcn_cvt_pkrtz(f[j] - (float)h[0], f[j + 1] - (float)h[1]);
        hi[j] = (_Float16)h[0]; hi[j + 1] = (_Float16)h[1];
        lo[j] = (_Float16)l[0]; lo[j + 1] = (_Float16)l[1];
    }
}

// hi-only pack of 4 floats
__device__ __forceinline__ f16x4 cvt4h(const float (&v)[4]) {
    f16x4 r;
    h16x2 a = __builtin_amdgcn_cvt_pkrtz(v[0], v[1]);
    h16x2 b = __builtin_amdgcn_cvt_pkrtz(v[2], v[3]);
    r[0] = (_Float16)a[0]; r[1] = (_Float16)a[1];
    r[2] = (_Float16)b[0]; r[3] = (_Float16)b[1];
    return r;
}

// one W B-frag slot, hi/lo selectable (validated r4-r7 layout)
__device__ __forceinline__ f16x8 wfrag_slot(const float* __restrict__ src, int kstep, int ct,
                                            int term, int mq, int qq) {
    f16x8 v;
#pragma unroll
    for (int j = 0; j < 8; ++j) {
        float wv = src[(kstep * 32 + qq * 8 + j) * 64 + ct * 16 + mq];
        _Float16 hi = (_Float16)wv;
        v[j] = term ? (_Float16)(wv - (float)hi) : hi;
    }
    return v;
}

// adjacency bytes (8) -> exact f16x8 A-fragment (validated r5-r7)
__device__ __forceinline__ f16x8 cvt_a8(uint2 v) {
    f16x8 r;
#pragma unroll
    for (int k = 0; k < 4; ++k) r[k] = (_Float16)(float)((v.x >> (8 * k)) & 255u);
#pragma unroll
    for (int k = 0; k < 4; ++k) r[4 + k] = (_Float16)(float)((v.y >> (8 * k)) & 255u);
    return r;
}

// ---------------------------------------------------------------------------
// k_adj: build per-graph dense u8 adjacency in GLOBAL memory with packed-byte
// atomics (A must be zeroed first). Edges never cross graphs (reference).
// Diagonal +1 = GCN self-loops. Row = dst, col = src.
// ---------------------------------------------------------------------------
__global__ __launch_bounds__(256) void k_adj(const int* __restrict__ ei, unsigned int* __restrict__ A) {
    int idx = blockIdx.x * 256 + threadIdx.x;
    if (idx < EE) {
        int s = ei[idx], d = ei[EE + idx];
        int g = s / NPGc;
        int ls = s - g * NPGc, ld = d - g * NPGc;
        int addr = g * ASTRIDE + ld * 224 + ls;
        atomicAdd(&A[addr >> 2], 1u << ((addr & 3) * 8));
    } else if (idx < EE + NN) {
        int n = idx - EE;
        int g = n / NPGc, ln = n - g * NPGc;
        int addr = g * ASTRIDE + ln * 225;
        atomicAdd(&A[addr >> 2], 1u << ((addr & 3) * 8));
    }
}

// ---------------------------------------------------------------------------
// k_xw: xW = x @ W1[0:128], 3-term hi/lo MFMA (exact; validated r4-r7 math).
// NEW: x tile staged in LDS via coalesced f32x4 loads (old path fetched ~4x
// amplified scattered 16B/lane). 128 rows/block, 512 thr, ~100KB LDS.
// ---------------------------------------------------------------------------
__global__ __launch_bounds__(512) void k_xw(const float* __restrict__ x,
                                            const float* __restrict__ w1,
                                            float* __restrict__ xW) {
    __shared__ __align__(16) float xs[128 * 132];        // stride 132 -> 2-way (free) on frag reads
    __shared__ __align__(16) _Float16 wf1[32 * 512];     // W1 hi chunks 0..15, lo 16..31

    int t = threadIdx.x;
    int rbase = blockIdx.x * 128;

    for (int i = t; i < 2048; i += 512) {
        int c = i >> 6, lane2 = i & 63;
        ((f16x8*)wf1)[i] = wfrag_slot(w1, c & 3, (c >> 2) & 3, c >> 4, lane2 & 15, lane2 >> 4);
    }
    // stage x tile: fully coalesced (32 lanes x 16B = one 512B row per wave-half)
    {
        int row = t >> 5, col4 = t & 31;
#pragma unroll
        for (int pass = 0; pass < 8; ++pass) {
            int r = pass * 16 + row;
            int grow = min(rbase + r, NN - 1);
            *(f32x4*)&xs[r * 132 + col4 * 4] = *(const f32x4*)(x + (size_t)grow * 128 + col4 * 4);
        }
    }
    __syncthreads();

    int lane = t & 63, w = t >> 6;
    int m = lane & 15, q = lane >> 4;
    int rowl = w * 16 + m;
    f16x8 Ah[4], Al[4];
#pragma unroll
    for (int ks = 0; ks < 4; ++ks) {
        f32x4 f0 = *(const f32x4*)&xs[rowl * 132 + ks * 32 + q * 8];
        f32x4 f1 = *(const f32x4*)&xs[rowl * 132 + ks * 32 + q * 8 + 4];
        cvt_hilo(f0, f1, Ah[ks], Al[ks]);
    }
    int rb = rbase + w * 16;
#pragma unroll
    for (int ct = 0; ct < 4; ++ct) {
        f32x4 acc = {0.f, 0.f, 0.f, 0.f};
#pragma unroll
        for (int ks = 0; ks < 4; ++ks) {
            f16x8 Bh = ((const f16x8*)wf1)[((0 * 4 + ct) * 4 + ks) * 64 + lane];
            f16x8 Bl = ((const f16x8*)wf1)[((1 * 4 + ct) * 4 + ks) * 64 + lane];
            acc = __builtin_amdgcn_mfma_f32_16x16x32_f16(Ah[ks], Bh, acc, 0, 0, 0);
            acc = __builtin_amdgcn_mfma_f32_16x16x32_f16(Al[ks], Bh, acc, 0, 0, 0);
            acc = __builtin_amdgcn_mfma_f32_16x16x32_f16(Ah[ks], Bl, acc, 0, 0, 0);
        }
#pragma unroll
        for (int i = 0; i < 4; ++i) {
            int r = rb + q * 4 + i;
            if (r < NN) xW[(size_t)r * 64 + ct * 16 + m] = acc[i];
        }
    }
}

// ---------------------------------------------------------------------------
// conv: D = A(adj f16 frags in VGPR) x T(hi f16 B-frags in LDS); epilogue
// relu(dv*acc + b) written as f16 A-frags (Hf) for the following gemm.
// r6 wave tiling: wave w owns m-tiles {w, w+8 (w<5)}; all 4 col-tiles.
// ---------------------------------------------------------------------------
template <bool POOL>
__device__ __forceinline__ void conv_mfma(const _Float16* __restrict__ Tfh,
                                          _Float16* __restrict__ Hf,
                                          const f16x8 (&Af)[2][7], int lane, int m, int q,
                                          int w, int nmt, const float* __restrict__ dv,
                                          const float* __restrict__ biasrow,
                                          float (&poolv)[4]) {
    f32x4 acc[2][4];
#pragma unroll
    for (int mi = 0; mi < 2; ++mi)
#pragma unroll
        for (int ct = 0; ct < 4; ++ct) acc[mi][ct] = (f32x4){0.f, 0.f, 0.f, 0.f};

#pragma unroll
    for (int ks = 0; ks < 7; ++ks) {
#pragma unroll
        for (int ct = 0; ct < 4; ++ct) {
            f16x8 Bh = ((const f16x8*)Tfh)[(ks * 4 + ct) * 64 + lane];
            acc[0][ct] = __builtin_amdgcn_mfma_f32_16x16x32_f16(Af[0][ks], Bh, acc[0][ct], 0, 0, 0);
            if (nmt > 1)
                acc[1][ct] = __builtin_amdgcn_mfma_f32_16x16x32_f16(Af[1][ks], Bh, acc[1][ct], 0, 0, 0);
        }
    }
#pragma unroll
    for (int mi = 0; mi < 2; ++mi) {
        if (mi >= nmt) break;
        int mt = w + 8 * mi;
        int rb = mt * 16 + q * 4;
        float dvi[4];
#pragma unroll
        for (int i = 0; i < 4; ++i) dvi[i] = dv[rb + i];
#pragma unroll
        for (int ct = 0; ct < 4; ++ct) {
            float bias = biasrow[ct * 16 + m];
            if (!POOL) {
#pragma unroll
                for (int i = 0; i < 4; ++i) {
                    float o = fmaxf(fmaf(dvi[i], acc[mi][ct][i], bias), 0.f);
                    // Hf chunk(mt, ct>>1): lane' = (r%16) + 16*((c%32)/8), j = c%8
                    Hf[(mt * 2 + (ct >> 1)) * 512 +
                       ((q * 4 + i) + 16 * ((ct & 1) * 2 + (m >> 3))) * 8 + (m & 7)] = (_Float16)o;
                }
            } else {
                float pl = 0.f;
#pragma unroll
                for (int i = 0; i < 4; ++i) {
                    float o = fmaxf(fmaf(dvi[i], acc[mi][ct][i], bias), 0.f);
                    if (rb + i < NPGc) pl += o;
                }
                poolv[ct] += pl;
            }
        }
    }
}

// ---------------------------------------------------------------------------
// gemm: T' = dv * (H @ W), H read as exact f16 A-frags from Hf (no cvt),
// W hi frags in LDS; output written directly as T B-frags (r6-validated map).
// ---------------------------------------------------------------------------
__device__ __forceinline__ void gemm_mfma(const _Float16* __restrict__ Hf,
                                          _Float16* __restrict__ Tfh,
                                          const _Float16* __restrict__ wf, int lane,
                                          int m, int q, int w, int nmt,
                                          const float* __restrict__ dv) {
#pragma unroll
    for (int mi = 0; mi < 2; ++mi) {
        if (mi >= nmt) break;
        int mt = w + 8 * mi;
        f16x8 Ah0 = ((const f16x8*)Hf)[(mt * 2 + 0) * 64 + lane];
        f16x8 Ah1 = ((const f16x8*)Hf)[(mt * 2 + 1) * 64 + lane];
        float dvi[4];
#pragma unroll
        for (int i = 0; i < 4; ++i) dvi[i] = dv[mt * 16 + q * 4 + i];
        int quad = (2 * mt + (q >> 1)) & 3;
        int j0 = (q & 1) << 2;
        int lanep = m + (quad << 4);
#pragma unroll
        for (int ct = 0; ct < 4; ++ct) {
            f32x4 acc = {0.f, 0.f, 0.f, 0.f};
            f16x8 B0 = ((const f16x8*)wf)[(ct * 2 + 0) * 64 + lane];
            f16x8 B1 = ((const f16x8*)wf)[(ct * 2 + 1) * 64 + lane];
            acc = __builtin_amdgcn_mfma_f32_16x16x32_f16(Ah0, B0, acc, 0, 0, 0);
            acc = __builtin_amdgcn_mfma_f32_16x16x32_f16(Ah1, B1, acc, 0, 0, 0);
            float o[4];
#pragma unroll
            for (int i = 0; i < 4; ++i) o[i] = acc[i] * dvi[i];
            *(f16x4*)(Tfh + ((mt >> 1) * 4 + ct) * 512 + lanep * 8 + j0) = cvt4h(o);
        }
    }
}

// ---------------------------------------------------------------------------
// Fused kernel: one block (512 thr, 8 waves) per graph. ~78 KB LDS ->
// 2 blocks/CU (4 waves/SIMD), all 500 blocks co-resident. Hi-only f16.
// ---------------------------------------------------------------------------
__global__ __launch_bounds__(512, 4) void k_fused(
    const float* __restrict__ xW, const float* __restrict__ perm,
    const float* __restrict__ w1,
    const float* __restrict__ b1, const float* __restrict__ b2, const float* __restrict__ b3,
    const float* __restrict__ w2, const float* __restrict__ w3,
    const unsigned char* __restrict__ Aall,
    const float* __restrict__ a1w, const float* __restrict__ a1b,
    const float* __restrict__ a2w, const float* __restrict__ a2b,
    float* __restrict__ out) {
    __shared__ __align__(16) _Float16 Tfh[28 * 512];   // T B-frags: chunk(ks0..6, ct0..3)  28KB
    __shared__ __align__(16) _Float16 Hf[26 * 512];    // H A-frags: chunk(mt0..12, ks2)    26KB
    __shared__ __align__(16) _Float16 wlds[16 * 512];  // W2 hi 0..7 (ct*2+ks), W3 hi 8..15 16KB
    __shared__ float w1r[640];
    __shared__ float dv[224];
    __shared__ float biasL[192];
    __shared__ float pool[8 * 64];
    __shared__ unsigned char idsl[672];

    int g = blockIdx.x, t = threadIdx.x;
    int lane = t & 63, w = t >> 6;
    int m = lane & 15, q = lane >> 4;
    int nmt = (w < 5) ? 2 : 1;
    int nbase = g * NPGc;

    // W2/W3 hi frags (global reads, L2-hot across 500 blocks)
    for (int i = t; i < 1024; i += 512) {
        int c = i >> 6, lane2 = i & 63;
        const float* src = (c >= 8) ? w3 : w2;
        int c4 = c & 7;
        ((f16x8*)wlds)[i] = wfrag_slot(src, c4 & 1, c4 >> 1, 0, lane2 & 15, lane2 >> 4);
    }
    for (int i = t; i < 640; i += 512) w1r[i] = w1[128 * 64 + i];
    if (t < 192) biasL[t] = (t < 64) ? b1[t] : ((t < 128) ? b2[t - 64] : b3[t - 128]);
    // one-hot ids for the 3 perms
    for (int i = t; i < 672; i += 512) {
        int p = i / 224, nd = i - p * 224;
        int id = 0;
        if (nd < NPGc) {
            const float* pp = perm + ((size_t)p * NN + nbase + nd) * 10;
            float best = pp[0];
#pragma unroll
            for (int k = 1; k < 10; ++k) { float v = pp[k]; if (v > best) { best = v; id = k; } }
        }
        idsl[i] = (unsigned char)id;
    }
    // adjacency A-frags from global slab + row sums -> dv
    const unsigned char* Ag = Aall + (size_t)g * ASTRIDE;
    f16x8 Af[2][7];
#pragma unroll
    for (int mi = 0; mi < 2; ++mi) {
        if (mi >= nmt) break;
        int mt = w + 8 * mi;
        unsigned s = 0;
#pragma unroll
        for (int ks = 0; ks < 7; ++ks) {
            uint2 v = *(const uint2*)(Ag + (mt * 16 + m) * 224 + ks * 32 + q * 8);
            Af[mi][ks] = cvt_a8(v);
            s += (v.x & 255u) + ((v.x >> 8) & 255u) + ((v.x >> 16) & 255u) + (v.x >> 24);
            s += (v.y & 255u) + ((v.y >> 8) & 255u) + ((v.y >> 16) & 255u) + (v.y >> 24);
        }
        float tot = (float)s;
        tot += __shfl_xor(tot, 16);
        tot += __shfl_xor(tot, 32);
        if (q == 0) dv[mt * 16 + m] = (tot > 0.f) ? rsqrtf(tot) : 0.f;
    }
    __syncthreads();

    float poolv[4] = {0.f, 0.f, 0.f, 0.f};

    for (int p = 0; p < NPERMc; ++p) {
        // conv1 input -> T hi frags: val = dv*(xW + w1row[id]); wave w: nodes [28w, 28w+28)
        {
            const unsigned char* ids = idsl + p * 224;
            for (int nd0 = w * 28; nd0 < w * 28 + 28; nd0 += 4) {
                float vals[4];
#pragma unroll
                for (int i = 0; i < 4; ++i) {
                    int nd = nd0 + i;
                    float v = 0.f;
                    if (nd < NPGc)
                        v = dv[nd] * (xW[(size_t)(nbase + nd) * 64 + lane] + w1r[ids[nd] * 64 + lane]);
                    vals[i] = v;
                }
                int c = (nd0 >> 5) * 4 + (lane >> 4);
                int lanep = (lane & 15) + (((nd0 & 31) >> 3) << 4);
                *(f16x4*)(Tfh + c * 512 + lanep * 8 + (nd0 & 7)) = cvt4h(vals);
            }
        }
        __syncthreads();
        conv_mfma<false>(Tfh, Hf, Af, lane, m, q, w, nmt, dv, biasL, poolv);        // conv1
        __syncthreads();
        gemm_mfma(Hf, Tfh, wlds, lane, m, q, w, nmt, dv);                           // @W2
        __syncthreads();
        conv_mfma<false>(Tfh, Hf, Af, lane, m, q, w, nmt, dv, biasL + 64, poolv);   // conv2
        __syncthreads();
        gemm_mfma(Hf, Tfh, wlds + 8 * 512, lane, m, q, w, nmt, dv);                 // @W3
        __syncthreads();
        conv_mfma<true>(Tfh, Hf, Af, lane, m, q, w, nmt, dv, biasL + 128, poolv);   // conv3+pool
        __syncthreads();
    }

    // reduce pool: q-groups (shfl) -> waves (LDS) -> head MLP
#pragma unroll
    for (int ct = 0; ct < 4; ++ct) {
        float v = poolv[ct];
        v += __shfl_xor(v, 16);
        v += __shfl_xor(v, 32);
        if (q == 0) pool[w * 64 + ct * 16 + m] = v;
    }
    __syncthreads();
    if (t < 64) {
        float tot = 0.f;
#pragma unroll
        for (int i = 0; i < 8; ++i) tot += pool[i * 64 + t];
        pool[t] = tot * (1.0f / (NPGc * NPERMc));   // graph vector
    }
    __syncthreads();
    if (t < 16) {
        float a = a1b[t];
        for (int k = 0; k < 64; ++k) a = fmaf(pool[k], a1w[k * 16 + t], a);
        pool[64 + t] = fmaxf(a, 0.f);
    }
    __syncthreads();
    if (t == 0) {
        float o = a2b[0];
#pragma unroll
        for (int i = 0; i < 16; ++i) o = fmaf(pool[64 + i], a2w[i], o);
        out[g] = o;
    }
}

// ---------------------------------------------------------------------------

static inline size_t alignup(size_t x) { return (x + 255) & ~(size_t)255; }

extern "C" void kernel_launch(void* const* d_in, const int* in_sizes, int n_in,
                              void* d_out, int out_size, void* d_ws, size_t ws_size,
                              hipStream_t stream) {
    const float* x    = (const float*)d_in[0];
    const int*   ei   = (const int*)d_in[1];
    // d_in[2] = batch_ids (unused: graphs are exactly 200 nodes each)
    const float* perm = (const float*)d_in[3];
    const float* w1   = (const float*)d_in[4];
    const float* b1   = (const float*)d_in[5];
    const float* w2   = (const float*)d_in[6];
    const float* b2   = (const float*)d_in[7];
    const float* w3   = (const float*)d_in[8];
    const float* b3   = (const float*)d_in[9];
    const float* a1w  = (const float*)d_in[10];
    const float* a1b  = (const float*)d_in[11];
    const float* a2w  = (const float*)d_in[12];
    const float* a2b  = (const float*)d_in[13];
    float* out = (float*)d_out;

    char* p = (char*)d_ws;
    auto take = [&](size_t bytes) { char* r = p; p += alignup(bytes); return r; };
    float*         xW   = (float*)take((size_t)NN * 64 * 4);
    unsigned char* Aall = (unsigned char*)take((size_t)GG * ASTRIDE);
    (void)hipMemsetAsync(Aall, 0, (size_t)GG * ASTRIDE, stream);

    k_adj<<<(EE + NN + 255) / 256, 256, 0, stream>>>(ei, (unsigned int*)Aall);
    k_xw<<<(NN + 127) / 128, 512, 0, stream>>>(x, w1, xW);
    k_fused<<<GG, 512, 0, stream>>>(xW, perm, w1, b1, b2, b3, w2, w3, Aall,
                                    a1w, a1b, a2w, a2b, out);
}

// Round 9
// 291.442 us; speedup vs baseline: 1.2303x; 1.0949x over previous
//
#include <hip/hip_runtime.h>

// Problem constants (from reference)
#define NN   100000
#define EE   1600000
#define GG   500
#define NPGc 200
#define NPERMc 3
#define C1   16384    // binning chunk (edges per block)
#define BSTRIDE 4096  // fixed token-bucket stride per graph
#define EB   98       // binning blocks

typedef __fp16   h16x2 __attribute__((ext_vector_type(2)));   // pkrtz result type
typedef _Float16 f16x4 __attribute__((ext_vector_type(4)));
typedef _Float16 f16x8 __attribute__((ext_vector_type(8)));
typedef float    f32x4 __attribute__((ext_vector_type(4)));

// ---------------------------------------------------------------------------
// f32 -> f16 hi/lo conversion (validated r4-r8; used in k_xw 3-term path)
// ---------------------------------------------------------------------------
__device__ __forceinline__ void cvt_hilo(f32x4 a, f32x4 b, f16x8& hi, f16x8& lo) {
    float f[8] = {a[0], a[1], a[2], a[3], b[0], b[1], b[2], b[3]};
#pragma unroll
    for (int j = 0; j < 8; j += 2) {
        h16x2 h = __builtin_amdgcn_cvt_pkrtz(f[j], f[j + 1]);
        h16x2 l = __builtin_amdgcn_cvt_pkrtz(f[j] - (float)h[0], f[j + 1] - (float)h[1]);
        hi[j] = (_Float16)h[0]; hi[j + 1] = (_Float16)h[1];
        lo[j] = (_Float16)l[0]; lo[j + 1] = (_Float16)l[1];
    }
}

// hi-only pack of 4 floats (validated r8)
__device__ __forceinline__ f16x4 cvt4h(const float (&v)[4]) {
    f16x4 r;
    h16x2 a = __builtin_amdgcn_cvt_pkrtz(v[0], v[1]);
    h16x2 b = __builtin_amdgcn_cvt_pkrtz(v[2], v[3]);
    r[0] = (_Float16)a[0]; r[1] = (_Float16)a[1];
    r[2] = (_Float16)b[0]; r[3] = (_Float16)b[1];
    return r;
}

// one W B-frag slot, hi/lo selectable (validated r4-r8 layout)
__device__ __forceinline__ f16x8 wfrag_slot(const float* __restrict__ src, int kstep, int ct,
                                            int term, int mq, int qq) {
    f16x8 v;
#pragma unroll
    for (int j = 0; j < 8; ++j) {
        float wv = src[(kstep * 32 + qq * 8 + j) * 64 + ct * 16 + mq];
        _Float16 hi = (_Float16)wv;
        v[j] = term ? (_Float16)(wv - (float)hi) : hi;
    }
    return v;
}

// adjacency bytes (8, packed in uint2) -> exact f16x8 A-fragment (validated r5-r8)
__device__ __forceinline__ f16x8 cvt_a8(uint2 v) {
    f16x8 r;
#pragma unroll
    for (int k = 0; k < 4; ++k) r[k] = (_Float16)(float)((v.x >> (8 * k)) & 255u);
#pragma unroll
    for (int k = 0; k < 4; ++k) r[4 + k] = (_Float16)(float)((v.y >> (8 * k)) & 255u);
    return r;
}

// ---------------------------------------------------------------------------
// k_bin: bin edges into fixed-stride per-graph u16 token buckets
// (token = lsrc | ldst<<8). Validated r5-r7.
// ---------------------------------------------------------------------------
__global__ __launch_bounds__(512) void k_bin(const int* __restrict__ ei, int* __restrict__ gcnt,
                                             unsigned short* __restrict__ gtok) {
    __shared__ unsigned short stag[C1];
    __shared__ int h[512], esc[512], cur[512], gb[512];
    int t = threadIdx.x;
    int base = blockIdx.x * C1;
    int nE = min(C1, EE - base);
    h[t] = 0; cur[t] = 0;
    __syncthreads();
    for (int i = t; i < nE; i += 512) atomicAdd(&h[ei[base + i] / NPGc], 1);
    __syncthreads();
    esc[t] = h[t];
    __syncthreads();
    for (int off = 1; off < 512; off <<= 1) {
        int u = (t >= off) ? esc[t - off] : 0;
        __syncthreads();
        esc[t] += u;
        __syncthreads();
    }
    esc[t] -= h[t];
    if (t < GG && h[t] > 0) gb[t] = atomicAdd(&gcnt[t], h[t]);
    __syncthreads();
    for (int i = t; i < nE; i += 512) {
        int s = ei[base + i], d = ei[EE + base + i];
        int g = s / NPGc;
        int ls = s - g * NPGc, ld = d - g * NPGc;
        int pos = esc[g] + atomicAdd(&cur[g], 1);
        stag[pos] = (unsigned short)(ls | (ld << 8));
    }
    __syncthreads();
    int w = t >> 6, lane = t & 63;
    for (int g = w; g < GG; g += 8) {
        int c = h[g]; if (!c) continue;
        int lb = esc[g], off = gb[g];
        int lim = min(c, BSTRIDE - off);
        for (int j = lane; j < lim; j += 64) gtok[(size_t)g * BSTRIDE + off + j] = stag[lb + j];
    }
}

// ---------------------------------------------------------------------------
// k_xw: xW = x @ W1[0:128], 3-term hi/lo MFMA, LDS-staged coalesced x loads
// (validated r8, unchanged).
// ---------------------------------------------------------------------------
__global__ __launch_bounds__(512) void k_xw(const float* __restrict__ x,
                                            const float* __restrict__ w1,
                                            float* __restrict__ xW) {
    __shared__ __align__(16) float xs[128 * 132];
    __shared__ __align__(16) _Float16 wf1[32 * 512];

    int t = threadIdx.x;
    int rbase = blockIdx.x * 128;

    for (int i = t; i < 2048; i += 512) {
        int c = i >> 6, lane2 = i & 63;
        ((f16x8*)wf1)[i] = wfrag_slot(w1, c & 3, (c >> 2) & 3, c >> 4, lane2 & 15, lane2 >> 4);
    }
    {
        int row = t >> 5, col4 = t & 31;
#pragma unroll
        for (int pass = 0; pass < 8; ++pass) {
            int r = pass * 16 + row;
            int grow = min(rbase + r, NN - 1);
            *(f32x4*)&xs[r * 132 + col4 * 4] = *(const f32x4*)(x + (size_t)grow * 128 + col4 * 4);
        }
    }
    __syncthreads();

    int lane = t & 63, w = t >> 6;
    int m = lane & 15, q = lane >> 4;
    int rowl = w * 16 + m;
    f16x8 Ah[4], Al[4];
#pragma unroll
    for (int ks = 0; ks < 4; ++ks) {
        f32x4 f0 = *(const f32x4*)&xs[rowl * 132 + ks * 32 + q * 8];
        f32x4 f1 = *(const f32x4*)&xs[rowl * 132 + ks * 32 + q * 8 + 4];
        cvt_hilo(f0, f1, Ah[ks], Al[ks]);
    }
    int rb = rbase + w * 16;
#pragma unroll
    for (int ct = 0; ct < 4; ++ct) {
        f32x4 acc = {0.f, 0.f, 0.f, 0.f};
#pragma unroll
        for (int ks = 0; ks < 4; ++ks) {
            f16x8 Bh = ((const f16x8*)wf1)[((0 * 4 + ct) * 4 + ks) * 64 + lane];
            f16x8 Bl = ((const f16x8*)wf1)[((1 * 4 + ct) * 4 + ks) * 64 + lane];
            acc = __builtin_amdgcn_mfma_f32_16x16x32_f16(Ah[ks], Bh, acc, 0, 0, 0);
            acc = __builtin_amdgcn_mfma_f32_16x16x32_f16(Al[ks], Bh, acc, 0, 0, 0);
            acc = __builtin_amdgcn_mfma_f32_16x16x32_f16(Ah[ks], Bl, acc, 0, 0, 0);
        }
#pragma unroll
        for (int i = 0; i < 4; ++i) {
            int r = rb + q * 4 + i;
            if (r < NN) xW[(size_t)r * 64 + ct * 16 + m] = acc[i];
        }
    }
}

// ---------------------------------------------------------------------------
// conv: D = A(packed-u8 frags in VGPR, cvt per use) x T(hi f16 B-frags in LDS);
// epilogue relu(dv*acc + b) written as f16 A-frags (Hf). r8-validated indexing.
// ---------------------------------------------------------------------------
template <bool POOL>
__device__ __forceinline__ void conv_mfma(const _Float16* __restrict__ Tfh,
                                          _Float16* __restrict__ Hf,
                                          const uint2 (&af)[2][7], int lane, int m, int q,
                                          int w, int nmt, const float* __restrict__ dv,
                                          const float* __restrict__ biasrow,
                                          float (&poolv)[4]) {
    f32x4 acc[2][4];
#pragma unroll
    for (int mi = 0; mi < 2; ++mi)
#pragma unroll
        for (int ct = 0; ct < 4; ++ct) acc[mi][ct] = (f32x4){0.f, 0.f, 0.f, 0.f};

#pragma unroll
    for (int ks = 0; ks < 7; ++ks) {
        f16x8 A0 = cvt_a8(af[0][ks]);
        f16x8 A1 = cvt_a8(af[1][ks]);   // dead if nmt==1 (af zeroed)
#pragma unroll
        for (int ct = 0; ct < 4; ++ct) {
            f16x8 Bh = ((const f16x8*)Tfh)[(ks * 4 + ct) * 64 + lane];
            acc[0][ct] = __builtin_amdgcn_mfma_f32_16x16x32_f16(A0, Bh, acc[0][ct], 0, 0, 0);
            if (nmt > 1)
                acc[1][ct] = __builtin_amdgcn_mfma_f32_16x16x32_f16(A1, Bh, acc[1][ct], 0, 0, 0);
        }
    }
#pragma unroll
    for (int mi = 0; mi < 2; ++mi) {
        if (mi >= nmt) break;
        int mt = w + 8 * mi;
        int rb = mt * 16 + q * 4;
        float dvi[4];
#pragma unroll
        for (int i = 0; i < 4; ++i) dvi[i] = dv[rb + i];
#pragma unroll
        for (int ct = 0; ct < 4; ++ct) {
            float bias = biasrow[ct * 16 + m];
            if (!POOL) {
#pragma unroll
                for (int i = 0; i < 4; ++i) {
                    float o = fmaxf(fmaf(dvi[i], acc[mi][ct][i], bias), 0.f);
                    Hf[(mt * 2 + (ct >> 1)) * 512 +
                       ((q * 4 + i) + 16 * ((ct & 1) * 2 + (m >> 3))) * 8 + (m & 7)] = (_Float16)o;
                }
            } else {
                float pl = 0.f;
#pragma unroll
                for (int i = 0; i < 4; ++i) {
                    float o = fmaxf(fmaf(dvi[i], acc[mi][ct][i], bias), 0.f);
                    if (rb + i < NPGc) pl += o;
                }
                poolv[ct] += pl;
            }
        }
    }
}

// ---------------------------------------------------------------------------
// gemm: T' = dv * (H @ W), H read as exact f16 A-frags, W hi frags in LDS;
// output written directly as T B-frags (r8-validated mapping).
// ---------------------------------------------------------------------------
__device__ __forceinline__ void gemm_mfma(const _Float16* __restrict__ Hf,
                                          _Float16* __restrict__ Tfh,
                                          const _Float16* __restrict__ wf, int lane,
                                          int m, int q, int w, int nmt,
                                          const float* __restrict__ dv) {
#pragma unroll
    for (int mi = 0; mi < 2; ++mi) {
        if (mi >= nmt) break;
        int mt = w + 8 * mi;
        f16x8 Ah0 = ((const f16x8*)Hf)[(mt * 2 + 0) * 64 + lane];
        f16x8 Ah1 = ((const f16x8*)Hf)[(mt * 2 + 1) * 64 + lane];
        float dvi[4];
#pragma unroll
        for (int i = 0; i < 4; ++i) dvi[i] = dv[mt * 16 + q * 4 + i];
        int quad = (2 * mt + (q >> 1)) & 3;
        int j0 = (q & 1) << 2;
        int lanep = m + (quad << 4);
#pragma unroll
        for (int ct = 0; ct < 4; ++ct) {
            f32x4 acc = {0.f, 0.f, 0.f, 0.f};
            f16x8 B0 = ((const f16x8*)wf)[(ct * 2 + 0) * 64 + lane];
            f16x8 B1 = ((const f16x8*)wf)[(ct * 2 + 1) * 64 + lane];
            acc = __builtin_amdgcn_mfma_f32_16x16x32_f16(Ah0, B0, acc, 0, 0, 0);
            acc = __builtin_amdgcn_mfma_f32_16x16x32_f16(Ah1, B1, acc, 0, 0, 0);
            float o[4];
#pragma unroll
            for (int i = 0; i < 4; ++i) o[i] = acc[i] * dvi[i];
            *(f16x4*)(Tfh + ((mt >> 1) * 4 + ct) * 512 + lanep * 8 + j0) = cvt4h(o);
        }
    }
}

// ---------------------------------------------------------------------------
// Fused kernel: one block (512 thr, 8 waves) per graph. Adjacency built in
// LDS from binned tokens (A8 region unions with Tfh/Hf); Af held as packed u8
// in 28 VGPRs. ~79 KB LDS -> 2 blocks/CU. Hi-only f16 (r8-validated precision).
// ---------------------------------------------------------------------------
__global__ __launch_bounds__(512, 4) void k_fused(
    const float* __restrict__ xW, const float* __restrict__ perm,
    const float* __restrict__ w1,
    const float* __restrict__ b1, const float* __restrict__ b2, const float* __restrict__ b3,
    const float* __restrict__ w2, const float* __restrict__ w3,
    const int* __restrict__ gcnt, const unsigned short* __restrict__ gtok,
    const float* __restrict__ a1w, const float* __restrict__ a1b,
    const float* __restrict__ a2w, const float* __restrict__ a2b,
    float* __restrict__ out) {
    __shared__ __align__(16) _Float16 TfHf[54 * 512];  // Tfh [0,28K), Hf [28K,54K); A8 build region
    __shared__ __align__(16) _Float16 wlds[16 * 512];  // W2 hi 0..7 (ct*2+ks), W3 hi 8..15
    __shared__ float w1r[640];
    __shared__ float dv[224];
    __shared__ float biasL[192];
    __shared__ float pool[8 * 64];
    __shared__ unsigned char idsl[672];

    _Float16* Tfh = TfHf;
    _Float16* Hf  = TfHf + 28 * 512;
    unsigned char* A8  = (unsigned char*)TfHf;   // 208*224 = 46592 B during build
    unsigned int*  A32 = (unsigned int*)TfHf;

    int g = blockIdx.x, t = threadIdx.x;
    int lane = t & 63, w = t >> 6;
    int m = lane & 15, q = lane >> 4;
    int nmt = (w < 5) ? 2 : 1;
    int nbase = g * NPGc;
    int cnt = min(gcnt[g], BSTRIDE);
    const unsigned short* tok = gtok + (size_t)g * BSTRIDE;

    // zero adjacency region first
    for (int i = t; i < 2912; i += 512) ((uint4*)A8)[i] = make_uint4(0, 0, 0, 0);
    __syncthreads();
    // build adjacency (u8 packed LDS atomics) + self-loops; stage small arrays
    for (int i = t; i < cnt; i += 512) {
        int tk = tok[i];
        int addr = (tk >> 8) * 224 + (tk & 255);
        atomicAdd(&A32[addr >> 2], 1u << ((addr & 3) * 8));
    }
    if (t < NPGc) { int a = t * 225; atomicAdd(&A32[a >> 2], 1u << ((a & 3) * 8)); }
    for (int i = t; i < 1024; i += 512) {
        int c = i >> 6, lane2 = i & 63;
        const float* src = (c >= 8) ? w3 : w2;
        int c4 = c & 7;
        ((f16x8*)wlds)[i] = wfrag_slot(src, c4 & 1, c4 >> 1, 0, lane2 & 15, lane2 >> 4);
    }
    for (int i = t; i < 640; i += 512) w1r[i] = w1[128 * 64 + i];
    if (t < 192) biasL[t] = (t < 64) ? b1[t] : ((t < 128) ? b2[t - 64] : b3[t - 128]);
    for (int i = t; i < 672; i += 512) {
        int p = i / 224, nd = i - p * 224;
        int id = 0;
        if (nd < NPGc) {
            const float* pp = perm + ((size_t)p * NN + nbase + nd) * 10;
            float best = pp[0];
#pragma unroll
            for (int k = 1; k < 10; ++k) { float v = pp[k]; if (v > best) { best = v; id = k; } }
        }
        idsl[i] = (unsigned char)id;
    }
    __syncthreads();
    // deg (row sums incl. self) -> dv
    if (t < 224) {
        unsigned s = 0;
        if (t < 208)
            for (int i = 0; i < 56; ++i) {
                unsigned v = A32[t * 56 + i];
                s += (v & 255u) + ((v >> 8) & 255u) + ((v >> 16) & 255u) + (v >> 24);
            }
        dv[t] = s ? rsqrtf((float)s) : 0.f;
    }
    // load adjacency into packed-u8 VGPRs (28 regs persistent)
    uint2 af[2][7];
#pragma unroll
    for (int mi = 0; mi < 2; ++mi) {
        int mt = w + 8 * mi;
#pragma unroll
        for (int ks = 0; ks < 7; ++ks)
            af[mi][ks] = (mi < nmt)
                ? *(const uint2*)(A8 + (mt * 16 + m) * 224 + ks * 32 + q * 8)
                : make_uint2(0u, 0u);
    }
    __syncthreads();   // A8 region dead -> Tfh/Hf take over

    float poolv[4] = {0.f, 0.f, 0.f, 0.f};

    for (int p = 0; p < NPERMc; ++p) {
        // conv1 input -> T hi frags: val = dv*(xW + w1row[id]); wave w: nodes [28w, 28w+28)
        {
            const unsigned char* ids = idsl + p * 224;
            for (int nd0 = w * 28; nd0 < w * 28 + 28; nd0 += 4) {
                float vals[4];
#pragma unroll
                for (int i = 0; i < 4; ++i) {
                    int nd = nd0 + i;
                    float v = 0.f;
                    if (nd < NPGc)
                        v = dv[nd] * (xW[(size_t)(nbase + nd) * 64 + lane] + w1r[ids[nd] * 64 + lane]);
                    vals[i] = v;
                }
                int c = (nd0 >> 5) * 4 + (lane >> 4);
                int lanep = (lane & 15) + (((nd0 & 31) >> 3) << 4);
                *(f16x4*)(Tfh + c * 512 + lanep * 8 + (nd0 & 7)) = cvt4h(vals);
            }
        }
        __syncthreads();
        conv_mfma<false>(Tfh, Hf, af, lane, m, q, w, nmt, dv, biasL, poolv);        // conv1
        __syncthreads();
        gemm_mfma(Hf, Tfh, wlds, lane, m, q, w, nmt, dv);                           // @W2
        __syncthreads();
        conv_mfma<false>(Tfh, Hf, af, lane, m, q, w, nmt, dv, biasL + 64, poolv);   // conv2
        __syncthreads();
        gemm_mfma(Hf, Tfh, wlds + 8 * 512, lane, m, q, w, nmt, dv);                 // @W3
        __syncthreads();
        conv_mfma<true>(Tfh, Hf, af, lane, m, q, w, nmt, dv, biasL + 128, poolv);   // conv3+pool
        __syncthreads();
    }

    // reduce pool: q-groups (shfl) -> waves (LDS) -> head MLP
#pragma unroll
    for (int ct = 0; ct < 4; ++ct) {
        float v = poolv[ct];
        v += __shfl_xor(v, 16);
        v += __shfl_xor(v, 32);
        if (q == 0) pool[w * 64 + ct * 16 + m] = v;
    }
    __syncthreads();
    if (t < 64) {
        float tot = 0.f;
#pragma unroll
        for (int i = 0; i < 8; ++i) tot += pool[i * 64 + t];
        pool[t] = tot * (1.0f / (NPGc * NPERMc));   // graph vector
    }
    __syncthreads();
    if (t < 16) {
        float a = a1b[t];
        for (int k = 0; k < 64; ++k) a = fmaf(pool[k], a1w[k * 16 + t], a);
        pool[64 + t] = fmaxf(a, 0.f);
    }
    __syncthreads();
    if (t == 0) {
        float o = a2b[0];
#pragma unroll
        for (int i = 0; i < 16; ++i) o = fmaf(pool[64 + i], a2w[i], o);
        out[g] = o;
    }
}

// ---------------------------------------------------------------------------

static inline size_t alignup(size_t x) { return (x + 255) & ~(size_t)255; }

extern "C" void kernel_launch(void* const* d_in, const int* in_sizes, int n_in,
                              void* d_out, int out_size, void* d_ws, size_t ws_size,
                              hipStream_t stream) {
    const float* x    = (const float*)d_in[0];
    const int*   ei   = (const int*)d_in[1];
    // d_in[2] = batch_ids (unused: graphs are exactly 200 nodes each)
    const float* perm = (const float*)d_in[3];
    const float* w1   = (const float*)d_in[4];
    const float* b1   = (const float*)d_in[5];
    const float* w2   = (const float*)d_in[6];
    const float* b2   = (const float*)d_in[7];
    const float* w3   = (const float*)d_in[8];
    const float* b3   = (const float*)d_in[9];
    const float* a1w  = (const float*)d_in[10];
    const float* a1b  = (const float*)d_in[11];
    const float* a2w  = (const float*)d_in[12];
    const float* a2b  = (const float*)d_in[13];
    float* out = (float*)d_out;

    char* p = (char*)d_ws;
    auto take = [&](size_t bytes) { char* r = p; p += alignup(bytes); return r; };
    float*          xW   = (float*)take((size_t)NN * 64 * 4);
    unsigned short* gtok = (unsigned short*)take((size_t)GG * BSTRIDE * 2);
    int*            gcnt = (int*)take(512 * 4);
    (void)hipMemsetAsync(gcnt, 0, 512 * 4, stream);

    k_bin<<<EB, 512, 0, stream>>>(ei, gcnt, gtok);
    k_xw<<<(NN + 127) / 128, 512, 0, stream>>>(x, w1, xW);
    k_fused<<<GG, 512, 0, stream>>>(xW, perm, w1, b1, b2, b3, w2, w3,
                                    gcnt, gtok, a1w, a1b, a2w, a2b, out);
}